// Round 1
// baseline (83.808 us; speedup 1.0000x reference)
//
#include <hip/hip_runtime.h>
#include <math.h>

// RadiusInteractionGraph: radius_graph(r=10, max_num_neighbors=32, per-molecule)
// + edge_weight = ||pos[src]-pos[tgt]||.
// Output layout (all float32): [ row (N*K) | col (N*K) | weight (N*K) ].
//
// Selection must bit-match the reference's stable top_k over
// d2 = sq_i + sq_j - 2*dot(pos_i, pos_j)  (Gram trick), so d2 is computed
// with explicit rounding-controlled ops:
//   sq  = (x*x + y*y) + z*z            (plain mul/add, no contraction)
//   dot = fmaf(z,z', fmaf(y,y', x*x')) (gemm k-loop fma accumulation order)
//   d2  = (sq_i + sq_j) - 2*dot
// Ties in d2 break by ascending index (stable top_k semantics).

#define KNBR 32
#define CUT2 100.0f
#define MAXT 8  // supports molecules up to MAXT*64 = 512 atoms (actual ~256±16)

__global__ __launch_bounds__(256) void radius_graph_kernel(
    const float* __restrict__ pos, const int* __restrict__ batch,
    float* __restrict__ out, const int n) {
  const int wave = threadIdx.x >> 6;
  const int lane = threadIdx.x & 63;
  const int i = (blockIdx.x << 2) + wave;  // one wave per target atom
  if (i >= n) return;

  const float xi = pos[3 * i + 0], yi = pos[3 * i + 1], zi = pos[3 * i + 2];
  const float sq_i =
      __fadd_rn(__fadd_rn(__fmul_rn(xi, xi), __fmul_rn(yi, yi)), __fmul_rn(zi, zi));
  const int m = batch[i];

  // Molecule bounds: batch is sorted ascending. Uniform binary search.
  int lo = 0, hi = n;
  while (lo < hi) { const int mid = (lo + hi) >> 1; if (batch[mid] < m) lo = mid + 1; else hi = mid; }
  const int s = lo;
  lo = 0; hi = n;
  while (lo < hi) { const int mid = (lo + hi) >> 1; if (batch[mid] <= m) lo = mid + 1; else hi = mid; }
  const int cnt = lo - s;  // molecule size (assumed <= MAXT*64)

  // Each lane owns candidates c = lane, lane+64, ... in registers (static idx).
  float d2r[MAXT];
#pragma unroll
  for (int t = 0; t < MAXT; ++t) {
    const int c = (t << 6) + lane;
    float d2 = INFINITY;  // INFINITY == invalid / out-of-cutoff
    if (c < cnt) {
      const int j = s + c;
      const float xj = pos[3 * j + 0], yj = pos[3 * j + 1], zj = pos[3 * j + 2];
      const float sq_j =
          __fadd_rn(__fadd_rn(__fmul_rn(xj, xj), __fmul_rn(yj, yj)), __fmul_rn(zj, zj));
      float dot = __fmul_rn(xi, xj);
      dot = __builtin_fmaf(yi, yj, dot);
      dot = __builtin_fmaf(zi, zj, dot);
      const float dd = __fsub_rn(__fadd_rn(sq_i, sq_j), __fmul_rn(2.0f, dot));
      if (j != i && dd <= CUT2) d2 = dd;
    }
    d2r[t] = d2;
  }

  // 32 passes of wave-wide lexicographic argmin over (d2, candidate index).
  int my_src = i;    // lane k holds edge slot k; default = self-loop padding
  int my_valid = 0;
  unsigned used = 0;  // per-lane bitmask over its MAXT slots
  for (int k = 0; k < KNBR; ++k) {
    float best = INFINITY;
    int bestc = 0x7fffffff;
#pragma unroll
    for (int t = 0; t < MAXT; ++t) {
      const int c = (t << 6) + lane;
      const float v = d2r[t];
      if (!((used >> t) & 1u) &&
          (v < best || (v == best && v < INFINITY && c < bestc))) {
        best = v;
        bestc = c;
      }
    }
    // Butterfly reduce: all lanes converge on the wave-wide (best, bestc).
#pragma unroll
    for (int off = 32; off; off >>= 1) {
      const float ov = __shfl_xor(best, off);
      const int oc = __shfl_xor(bestc, off);
      if (ov < best || (ov == best && oc < bestc)) { best = ov; bestc = oc; }
    }
    const bool sel = best < INFINITY;
    if (sel && (bestc & 63) == lane) used |= 1u << (bestc >> 6);
    if (lane == k) { my_src = sel ? s + bestc : i; my_valid = sel ? 1 : 0; }
  }

  // Epilogue: lanes 0..31 write edge slots 0..31 (coalesced 32-float runs).
  if (lane < KNBR) {
    float w = 0.0f;
    if (my_valid) {
      const float xj = pos[3 * my_src + 0], yj = pos[3 * my_src + 1],
                  zj = pos[3 * my_src + 2];
      const float dx = __fsub_rn(xj, xi), dy = __fsub_rn(yj, yi),
                  dz = __fsub_rn(zj, zi);
      const float d2e =
          __fadd_rn(__fadd_rn(__fmul_rn(dx, dx), __fmul_rn(dy, dy)), __fmul_rn(dz, dz));
      w = sqrtf(d2e);
    }
    const size_t nk = (size_t)n * KNBR;
    const size_t base = (size_t)i * KNBR + lane;
    out[base] = (float)my_src;            // row (source)
    out[nk + base] = (float)i;            // col (target)
    out[2 * nk + base] = w;               // edge_weight
  }
}

extern "C" void kernel_launch(void* const* d_in, const int* in_sizes, int n_in,
                              void* d_out, int out_size, void* d_ws, size_t ws_size,
                              hipStream_t stream) {
  const float* pos = (const float*)d_in[0];
  const int* batch = (const int*)d_in[1];
  float* out = (float*)d_out;
  const int n = in_sizes[0] / 3;        // pos is [N,3]
  const int blocks = (n + 3) / 4;       // 4 waves (targets) per 256-thread block
  radius_graph_kernel<<<blocks, 256, 0, stream>>>(pos, batch, out, n);
}